// Round 4
// baseline (681.375 us; speedup 1.0000x reference)
//
#include <hip/hip_runtime.h>
#include <hip/hip_fp16.h>

// Problem constants (fixed by the reference)
#define S_LEN 1024
#define N_B   64
#define H_DIM 1024
#define I_DIM 1024

typedef __attribute__((ext_vector_type(8))) _Float16 half8;
typedef __attribute__((ext_vector_type(4))) _Float16 half4;
typedef __attribute__((ext_vector_type(4))) float    f32x4;

// ---------------------------------------------------------------------------
// async global->LDS 16B helper (wave-uniform LDS base + lane*16 layout)
// ---------------------------------------------------------------------------
__device__ __forceinline__ void gload16(const void* g, void* l) {
  __builtin_amdgcn_global_load_lds(
      (const __attribute__((address_space(1))) unsigned int*)g,
      (__attribute__((address_space(3))) unsigned int*)l, 16, 0, 0);
}

// ---------------------------------------------------------------------------
// fp32 -> fp16 convert; 32B loads / 16B stores per lane per iter
// ---------------------------------------------------------------------------
__global__ void cvt_f32_f16(const float* __restrict__ src,
                            _Float16* __restrict__ dst, int n8) {
  int idx = blockIdx.x * blockDim.x + threadIdx.x;
  int stride = gridDim.x * blockDim.x;
  const float4* s4 = (const float4*)src;
  half8* d8 = (half8*)dst;
  for (int i = idx; i < n8; i += stride) {
    float4 a = s4[2 * i], b = s4[2 * i + 1];
    half8 h;
    h[0] = (_Float16)a.x; h[1] = (_Float16)a.y;
    h[2] = (_Float16)a.z; h[3] = (_Float16)a.w;
    h[4] = (_Float16)b.x; h[5] = (_Float16)b.y;
    h[6] = (_Float16)b.z; h[7] = (_Float16)b.w;
    d8[i] = h;
  }
}

// ---------------------------------------------------------------------------
// u1[n][i] = hidden_d[n]·W1[i] + b1[i] + b2[i]   (fp32, tiny GEMM)
// ---------------------------------------------------------------------------
__global__ void u1_kernel(const float* __restrict__ hd,
                          const float* __restrict__ W1,
                          const float* __restrict__ b1,
                          const float* __restrict__ b2,
                          float* __restrict__ u1) {
  __shared__ float hs[4 * 1024];
  int nb = blockIdx.x & 15;
  int ib = blockIdx.x >> 4;
  int t = threadIdx.x;
  int n0 = nb * 4;

  const float4* g4 = (const float4*)(hd + (size_t)n0 * 1024);
  float4* h4 = (float4*)hs;
#pragma unroll
  for (int r = 0; r < 4; ++r) h4[r * 256 + t] = g4[r * 256 + t];
  __syncthreads();

  int il = t >> 2, q = t & 3;
  int i = ib * 64 + il;
  const float4* w4 = (const float4*)(W1 + (size_t)i * 1024 + q * 256);
  float s0 = 0.f, s1 = 0.f, s2 = 0.f, s3 = 0.f;
  for (int hh = 0; hh < 64; ++hh) {
    float4 wv = w4[hh];
    int hb = q * 256 + hh * 4;
    float4 v0 = *(const float4*)&hs[0 * 1024 + hb];
    float4 v1 = *(const float4*)&hs[1 * 1024 + hb];
    float4 v2 = *(const float4*)&hs[2 * 1024 + hb];
    float4 v3 = *(const float4*)&hs[3 * 1024 + hb];
    s0 += wv.x * v0.x + wv.y * v0.y + wv.z * v0.z + wv.w * v0.w;
    s1 += wv.x * v1.x + wv.y * v1.y + wv.z * v1.z + wv.w * v1.w;
    s2 += wv.x * v2.x + wv.y * v2.y + wv.z * v2.z + wv.w * v2.w;
    s3 += wv.x * v3.x + wv.y * v3.y + wv.z * v3.z + wv.w * v3.w;
  }
  s0 += __shfl_xor(s0, 1); s0 += __shfl_xor(s0, 2);
  s1 += __shfl_xor(s1, 1); s1 += __shfl_xor(s1, 2);
  s2 += __shfl_xor(s2, 1); s2 += __shfl_xor(s2, 2);
  s3 += __shfl_xor(s3, 1); s3 += __shfl_xor(s3, 2);
  if (q == 0) {
    float bb = b1[i] + b2[i];
    u1[(size_t)(n0 + 0) * 1024 + i] = s0 + bb;
    u1[(size_t)(n0 + 1) * 1024 + i] = s1 + bb;
    u1[(size_t)(n0 + 2) * 1024 + i] = s2 + bb;
    u1[(size_t)(n0 + 3) * 1024 + i] = s3 + bb;
  }
}

// ---------------------------------------------------------------------------
// Main fused kernel: a_ws[m] += sum_i W3[i]*tanh(A[m]·W2[i] + u1[m&63][i])
// 256x256 tile, BK=32, K=1024 -> 32 k-tiles. 8 waves (2Mx4N).
// 2-deep counted-vmcnt pipeline:
//   - raw s_barrier (no compiler vmcnt(0) drain)
//   - vmcnt(4) gate per K-tile (tile k+1 stays in flight), vmcnt(0) only last
//   - stage tile k+2 after lgkmcnt(0)+barrier (buffer k&1 free by then)
//   - setprio(1) around MFMA clusters
// grid: 1024 blocks; XCD swizzle keeps the 4 cb of one A-panel on one XCD.
// ---------------------------------------------------------------------------
__global__ __launch_bounds__(512) void fused_gemm_tanh(
    const _Float16* __restrict__ A,   // [65536][1024] out_e fp16
    const _Float16* __restrict__ B,   // [1024][1024]  W2 fp16
    const float* __restrict__ u1,     // [64][1024] includes b1+b2
    const float* __restrict__ W3,     // [1024]
    float* __restrict__ a_ws)         // [65536] pre-zeroed, atomic target
{
  __shared__ __align__(16) _Float16 As[2][256 * 32];  // 32 KB
  __shared__ __align__(16) _Float16 Bs[2][256 * 32];  // 32 KB

  const int t = threadIdx.x;           // 0..511
  const int lane = t & 63;
  const int w = t >> 6;                // 0..7
  const int wr = w >> 2, wc = w & 3;   // 2 x 4 wave grid
  const int bx = blockIdx.x;
  const int xcd = bx & 7;
  const int j = bx >> 3;               // 0..127
  const int rb = xcd + ((j >> 2) << 3);  // 0..255
  const int cb = j & 3;                  // 0..3
  const int m0 = rb * 256, i0 = cb * 256;

  const int fr = lane & 15;            // fragment row (A-row / B-col)
  const int kg = lane >> 4;            // k-group 0..3

  // staging map: thread t covers (row t>>2 [+128 on round 1], 16B-unit t&3)
  const int srow = t >> 2, sunit = t & 3;
  const _Float16* gA = A + (size_t)(m0 + srow) * 1024 + sunit * 8;
  const _Float16* gB = B + (size_t)(i0 + srow) * 1024 + sunit * 8;
  const int ldst = t * 8;              // halves; LDS byte off = t*16 (linear)

#define STAGE(kt) do { int b2 = (kt) & 1; int kc = (kt) * 32;       \
    gload16(gA + kc,               &As[b2][ldst]);                   \
    gload16(gA + kc + 128 * 1024,  &As[b2][ldst + 4096]);            \
    gload16(gB + kc,               &Bs[b2][ldst]);                   \
    gload16(gB + kc + 128 * 1024,  &Bs[b2][ldst + 4096]); } while (0)

  f32x4 acc[8][4] = {};

  STAGE(0);
  STAGE(1);

  const int aoff = (wr * 128 + fr) * 32 + kg * 8;  // + (mh*4+mi)*512
  const int boff = (wc * 64 + fr) * 32 + kg * 8;   // + ni*512

  for (int kt = 0; kt < 32; ++kt) {     // 32 k-tiles: full K=1024
    const int b = kt & 1;
    // gate: this tile's 4 loads landed; next tile's 4 may stay in flight
    if (kt == 31)
      asm volatile("s_waitcnt vmcnt(0)" ::: "memory");
    else
      asm volatile("s_waitcnt vmcnt(4)" ::: "memory");
    __builtin_amdgcn_s_barrier();
    asm volatile("" ::: "memory");

    half8 bf[4];
#pragma unroll
    for (int ni = 0; ni < 4; ++ni)
      bf[ni] = *(const half8*)&Bs[b][boff + ni * 512];
#pragma unroll
    for (int mh = 0; mh < 2; ++mh) {
      half8 af[4];
#pragma unroll
      for (int mi = 0; mi < 4; ++mi)
        af[mi] = *(const half8*)&As[b][aoff + (mh * 4 + mi) * 512];
      __builtin_amdgcn_s_setprio(1);
#pragma unroll
      for (int mi = 0; mi < 4; ++mi)
#pragma unroll
        for (int ni = 0; ni < 4; ++ni)
          acc[mh * 4 + mi][ni] = __builtin_amdgcn_mfma_f32_16x16x32_f16(
              af[mi], bf[ni], acc[mh * 4 + mi][ni], 0, 0, 0);
      __builtin_amdgcn_s_setprio(0);
    }
    // all ds_reads of buf b complete before anyone overwrites it
    asm volatile("s_waitcnt lgkmcnt(0)" ::: "memory");
    __builtin_amdgcn_s_barrier();
    asm volatile("" ::: "memory");
    if (kt < 30) STAGE(kt + 2);
  }
#undef STAGE

  // Epilogue: e = acc + u1; tanh; dot with W3; reduce over fr lanes; atomic.
  float w3v[4];
#pragma unroll
  for (int ni = 0; ni < 4; ++ni)
    w3v[ni] = W3[i0 + wc * 64 + ni * 16 + fr];
  const float* u1base = u1 + i0 + wc * 64 + fr;

#pragma unroll
  for (int mi = 0; mi < 8; ++mi) {
#pragma unroll
    for (int jj = 0; jj < 4; ++jj) {
      int m = m0 + wr * 128 + mi * 16 + kg * 4 + jj;  // C/D row=(lane>>4)*4+reg
      const float* u1row = u1base + (size_t)(m & 63) * 1024;
      float s = 0.f;
#pragma unroll
      for (int ni = 0; ni < 4; ++ni) {
        float e = acc[mi][ni][jj] + u1row[ni * 16];   // C/D col=lane&15
        float th = 1.f - 2.f / (__expf(2.f * e) + 1.f);  // tanh, inf/0-safe
        s += th * w3v[ni];
      }
      s += __shfl_xor(s, 1);
      s += __shfl_xor(s, 2);
      s += __shfl_xor(s, 4);
      s += __shfl_xor(s, 8);
      if (fr == 0) atomicAdd(&a_ws[m], s);
    }
  }
}

// ---------------------------------------------------------------------------
// softmax over s for each n (b3 omitted: scalar shift is softmax-invariant)
// ---------------------------------------------------------------------------
__global__ void softmax_col(const float* __restrict__ a_ws,
                            float* __restrict__ alpha) {
  int n = blockIdx.x;
  int t = threadIdx.x;
  __shared__ float red[256];
  float v[4];
  float mx = -1e30f;
#pragma unroll
  for (int q = 0; q < 4; ++q) {
    v[q] = a_ws[(size_t)(t + q * 256) * 64 + n];
    mx = fmaxf(mx, v[q]);
  }
  red[t] = mx; __syncthreads();
  for (int off = 128; off > 0; off >>= 1) {
    if (t < off) red[t] = fmaxf(red[t], red[t + off]);
    __syncthreads();
  }
  mx = red[0];
  __syncthreads();
  float sum = 0.f;
#pragma unroll
  for (int q = 0; q < 4; ++q) { v[q] = __expf(v[q] - mx); sum += v[q]; }
  red[t] = sum; __syncthreads();
  for (int off = 128; off > 0; off >>= 1) {
    if (t < off) red[t] += red[t + off];
    __syncthreads();
  }
  float inv = 1.f / red[0];
#pragma unroll
  for (int q = 0; q < 4; ++q)
    alpha[(size_t)(t + q * 256) * 64 + n] = v[q] * inv;
}

// ---------------------------------------------------------------------------
// c[n][h] += sum_{s in chunk sc} alpha[s,n] * oe16[s,n,h]
// ---------------------------------------------------------------------------
__global__ void weighted_sum(const _Float16* __restrict__ oe,
                             const float* __restrict__ alpha,
                             float* __restrict__ cout) {
  int n = blockIdx.x & 63;
  int sc = blockIdx.x >> 6;
  int t = threadIdx.x;
  __shared__ float al[64];
  if (t < 64) al[t] = alpha[(size_t)(sc * 64 + t) * 64 + n];
  __syncthreads();
  float a0 = 0.f, a1 = 0.f, a2 = 0.f, a3 = 0.f;
#pragma unroll 4
  for (int sl = 0; sl < 64; ++sl) {
    float a = al[sl];
    int s = sc * 64 + sl;
    half4 x = *(const half4*)(oe + (size_t)(s * 64 + n) * 1024 + t * 4);
    a0 += a * (float)x[0]; a1 += a * (float)x[1];
    a2 += a * (float)x[2]; a3 += a * (float)x[3];
  }
  float* c = cout + (size_t)n * 1024 + t * 4;
  atomicAdd(c + 0, a0);
  atomicAdd(c + 1, a1);
  atomicAdd(c + 2, a2);
  atomicAdd(c + 3, a3);
}

// ---------------------------------------------------------------------------
extern "C" void kernel_launch(void* const* d_in, const int* in_sizes, int n_in,
                              void* d_out, int out_size, void* d_ws,
                              size_t ws_size, hipStream_t stream) {
  const float* out_e    = (const float*)d_in[0];
  const float* hidden_d = (const float*)d_in[1];
  const float* W1       = (const float*)d_in[2];
  const float* b1       = (const float*)d_in[3];
  const float* W2       = (const float*)d_in[4];
  const float* b2       = (const float*)d_in[5];
  const float* W3       = (const float*)d_in[6];
  // d_in[7] = b3: scalar shift before softmax -> cancels; unused.

  char* ws = (char*)d_ws;
  _Float16* oe16 = (_Float16*)ws;                               // 128 MB
  _Float16* w216 = (_Float16*)(ws + 134217728);                 // 2 MB
  float* u1   = (float*)(ws + 134217728 + 2097152);             // 256 KB
  float* a_ws = (float*)(ws + 134217728 + 2097152 + 262144);    // 256 KB

  float* c_out = (float*)d_out;            // [64][1024]
  float* alpha = (float*)d_out + 65536;    // [1024][64]

  hipLaunchKernelGGL(cvt_f32_f16, dim3(2048), dim3(256), 0, stream,
                     out_e, oe16, 67108864 / 8);
  hipLaunchKernelGGL(cvt_f32_f16, dim3(512), dim3(256), 0, stream,
                     W2, w216, 1048576 / 8);
  hipLaunchKernelGGL(u1_kernel, dim3(256), dim3(256), 0, stream,
                     hidden_d, W1, b1, b2, u1);
  hipMemsetAsync(a_ws, 0, 65536 * 4, stream);
  hipMemsetAsync(c_out, 0, 65536 * 4, stream);
  hipLaunchKernelGGL(fused_gemm_tanh, dim3(1024), dim3(512), 0, stream,
                     oe16, w216, u1, W3, a_ws);
  hipLaunchKernelGGL(softmax_col, dim3(64), dim3(256), 0, stream,
                     a_ws, alpha);
  hipLaunchKernelGGL(weighted_sum, dim3(1024), dim3(256), 0, stream,
                     oe16, alpha, c_out);
}

// Round 5
// 666.400 us; speedup vs baseline: 1.0225x; 1.0225x over previous
//
#include <hip/hip_runtime.h>
#include <hip/hip_fp16.h>

// Problem constants (fixed by the reference)
#define S_LEN 1024
#define N_B   64
#define H_DIM 1024
#define I_DIM 1024

typedef __attribute__((ext_vector_type(8))) _Float16 half8;
typedef __attribute__((ext_vector_type(4))) _Float16 half4;
typedef __attribute__((ext_vector_type(4))) float    f32x4;

// ---------------------------------------------------------------------------
// async global->LDS 16B helper (wave-uniform LDS base + lane*16 layout)
// ---------------------------------------------------------------------------
__device__ __forceinline__ void gload16(const void* g, void* l) {
  __builtin_amdgcn_global_load_lds(
      (const __attribute__((address_space(1))) unsigned int*)g,
      (__attribute__((address_space(3))) unsigned int*)l, 16, 0, 0);
}

// ---------------------------------------------------------------------------
// fp32 -> fp16 convert; 32B loads / 16B stores per lane per iter
// ---------------------------------------------------------------------------
__global__ void cvt_f32_f16(const float* __restrict__ src,
                            _Float16* __restrict__ dst, int n8) {
  int idx = blockIdx.x * blockDim.x + threadIdx.x;
  int stride = gridDim.x * blockDim.x;
  const float4* s4 = (const float4*)src;
  half8* d8 = (half8*)dst;
  for (int i = idx; i < n8; i += stride) {
    float4 a = s4[2 * i], b = s4[2 * i + 1];
    half8 h;
    h[0] = (_Float16)a.x; h[1] = (_Float16)a.y;
    h[2] = (_Float16)a.z; h[3] = (_Float16)a.w;
    h[4] = (_Float16)b.x; h[5] = (_Float16)b.y;
    h[6] = (_Float16)b.z; h[7] = (_Float16)b.w;
    d8[i] = h;
  }
}

// ---------------------------------------------------------------------------
// u1[n][i] = hidden_d[n]·W1[i] + b1[i] + b2[i]   (fp32, tiny GEMM)
// Also zero-inits a_ws (65536 = grid*block exactly; runs before GEMM).
// ---------------------------------------------------------------------------
__global__ void u1_kernel(const float* __restrict__ hd,
                          const float* __restrict__ W1,
                          const float* __restrict__ b1,
                          const float* __restrict__ b2,
                          float* __restrict__ u1,
                          float* __restrict__ a_ws) {
  __shared__ float hs[4 * 1024];
  int nb = blockIdx.x & 15;
  int ib = blockIdx.x >> 4;
  int t = threadIdx.x;
  int n0 = nb * 4;

  a_ws[blockIdx.x * 256 + t] = 0.f;   // zero-init atomic target

  const float4* g4 = (const float4*)(hd + (size_t)n0 * 1024);
  float4* h4 = (float4*)hs;
#pragma unroll
  for (int r = 0; r < 4; ++r) h4[r * 256 + t] = g4[r * 256 + t];
  __syncthreads();

  int il = t >> 2, q = t & 3;
  int i = ib * 64 + il;
  const float4* w4 = (const float4*)(W1 + (size_t)i * 1024 + q * 256);
  float s0 = 0.f, s1 = 0.f, s2 = 0.f, s3 = 0.f;
  for (int hh = 0; hh < 64; ++hh) {
    float4 wv = w4[hh];
    int hb = q * 256 + hh * 4;
    float4 v0 = *(const float4*)&hs[0 * 1024 + hb];
    float4 v1 = *(const float4*)&hs[1 * 1024 + hb];
    float4 v2 = *(const float4*)&hs[2 * 1024 + hb];
    float4 v3 = *(const float4*)&hs[3 * 1024 + hb];
    s0 += wv.x * v0.x + wv.y * v0.y + wv.z * v0.z + wv.w * v0.w;
    s1 += wv.x * v1.x + wv.y * v1.y + wv.z * v1.z + wv.w * v1.w;
    s2 += wv.x * v2.x + wv.y * v2.y + wv.z * v2.z + wv.w * v2.w;
    s3 += wv.x * v3.x + wv.y * v3.y + wv.z * v3.z + wv.w * v3.w;
  }
  s0 += __shfl_xor(s0, 1); s0 += __shfl_xor(s0, 2);
  s1 += __shfl_xor(s1, 1); s1 += __shfl_xor(s1, 2);
  s2 += __shfl_xor(s2, 1); s2 += __shfl_xor(s2, 2);
  s3 += __shfl_xor(s3, 1); s3 += __shfl_xor(s3, 2);
  if (q == 0) {
    float bb = b1[i] + b2[i];
    u1[(size_t)(n0 + 0) * 1024 + i] = s0 + bb;
    u1[(size_t)(n0 + 1) * 1024 + i] = s1 + bb;
    u1[(size_t)(n0 + 2) * 1024 + i] = s2 + bb;
    u1[(size_t)(n0 + 3) * 1024 + i] = s3 + bb;
  }
}

// ---------------------------------------------------------------------------
// Main fused kernel:  a_ws[m] += sum_i W3[i] * tanh( A[m]·W2[i] + u1[m&63][i] )
// R2-proven m97 structure: 128x128 tile, BK=32, 4 waves (2x2), 16x16x32 fp16
// MFMA, double-buffered LDS via global_load_lds width-16.
// NEW (T2): unit-XOR LDS swizzle — linear LDS dest, inverse-swizzled GLOBAL
// source, swizzled ds_read (rule #21c). LDS tile [128][32] fp16: each 64B row
// = 4 x 16B units; store unit u holds logical unit u^(row&3); read uses
// kg^(fr&3). Cuts the 8-way ds_read_b128 bank conflict to 4-way.
// grid: 4096 blocks; XCD swizzle keeps one A-panel's 8 cb on one XCD.
// ---------------------------------------------------------------------------
__global__ __launch_bounds__(256) void fused_gemm_tanh(
    const _Float16* __restrict__ A,   // [65536][1024] out_e fp16
    const _Float16* __restrict__ B,   // [1024][1024]  W2 fp16
    const float* __restrict__ u1,     // [64][1024] includes b1+b2
    const float* __restrict__ W3,     // [1024]
    float* __restrict__ a_ws)         // [65536] pre-zeroed, atomic target
{
  __shared__ __align__(16) _Float16 As[2][128 * 32];  // 8KB per buf
  __shared__ __align__(16) _Float16 Bs[2][128 * 32];

  const int t = threadIdx.x;
  const int lane = t & 63;
  const int w = t >> 6;
  const int wr = w >> 1, wc = w & 1;
  const int bx = blockIdx.x;
  const int xcd = bx & 7;
  const int j = bx >> 3;
  const int rb = xcd + ((j >> 3) << 3);   // 0..511
  const int cb = j & 7;                   // 0..7
  const int m0 = rb * 128, i0 = cb * 128;

  // staging: thread t -> LDS row t>>2 (+64 on 2nd call), linear unit t&3.
  // Global source unit is pre-swizzled: (t&3) ^ ((t>>2)&3)  [involution]
  const int strow = t >> 2;
  const int stcol = ((t & 3) ^ ((t >> 2) & 3)) * 8;   // fp16 elems
  const _Float16* gA = A + (size_t)(m0 + strow) * 1024 + stcol;
  const _Float16* gB = B + (size_t)(i0 + strow) * 1024 + stcol;
  const int ldsoff = strow * 32 + (t & 3) * 8;  // linear dest: byte = t*16

  f32x4 acc[4][4] = {};

  gload16(gA,             &As[0][ldsoff]);
  gload16(gA + 64 * 1024, &As[0][ldsoff + 64 * 32]);
  gload16(gB,             &Bs[0][ldsoff]);
  gload16(gB + 64 * 1024, &Bs[0][ldsoff + 64 * 32]);
  __syncthreads();  // compiler drains vmcnt before s_barrier

  const int fr = lane & 15;     // A-row / B-col within fragment
  const int kg = lane >> 4;     // k-group 0..3 (8 contiguous k each)
  // swizzled read unit: kg ^ (fr&3); row&3 == fr&3 for all mi/ni offsets
  const int un = (kg ^ (fr & 3)) * 8;
  const int aoff = (wr * 64 + fr) * 32 + un;
  const int boff = (wc * 64 + fr) * 32 + un;

  for (int kt = 0; kt < 32; ++kt) {
    const int buf = kt & 1;
    if (kt < 31) {  // prefetch next k-tile into other buffer (swizzled src)
      const _Float16* gA2 = gA + (kt + 1) * 32;
      const _Float16* gB2 = gB + (kt + 1) * 32;
      gload16(gA2,             &As[buf ^ 1][ldsoff]);
      gload16(gA2 + 64 * 1024, &As[buf ^ 1][ldsoff + 64 * 32]);
      gload16(gB2,             &Bs[buf ^ 1][ldsoff]);
      gload16(gB2 + 64 * 1024, &Bs[buf ^ 1][ldsoff + 64 * 32]);
    }
    half8 af[4], bf[4];
#pragma unroll
    for (int mi = 0; mi < 4; ++mi)
      af[mi] = *(const half8*)&As[buf][aoff + mi * 16 * 32];
#pragma unroll
    for (int ni = 0; ni < 4; ++ni)
      bf[ni] = *(const half8*)&Bs[buf][boff + ni * 16 * 32];
#pragma unroll
    for (int mi = 0; mi < 4; ++mi)
#pragma unroll
      for (int ni = 0; ni < 4; ++ni)
        acc[mi][ni] = __builtin_amdgcn_mfma_f32_16x16x32_f16(
            af[mi], bf[ni], acc[mi][ni], 0, 0, 0);
    __syncthreads();
  }

  // Epilogue: e = acc + u1; tanh; dot with W3; reduce over fr lanes; atomic.
  float w3v[4];
#pragma unroll
  for (int ni = 0; ni < 4; ++ni)
    w3v[ni] = W3[i0 + wc * 64 + ni * 16 + fr];

#pragma unroll
  for (int mi = 0; mi < 4; ++mi) {
#pragma unroll
    for (int jj = 0; jj < 4; ++jj) {
      int m = m0 + wr * 64 + mi * 16 + kg * 4 + jj;  // C/D row=(lane>>4)*4+reg
      int n = m & 63;
      const float* u1row = u1 + (size_t)n * 1024 + i0 + wc * 64;
      float s = 0.f;
#pragma unroll
      for (int ni = 0; ni < 4; ++ni) {
        float e = acc[mi][ni][jj] + u1row[ni * 16 + fr];  // C/D col=lane&15
        float th = 1.f - 2.f / (__expf(2.f * e) + 1.f);   // tanh, inf/0-safe
        s += th * w3v[ni];
      }
      s += __shfl_xor(s, 1);
      s += __shfl_xor(s, 2);
      s += __shfl_xor(s, 4);
      s += __shfl_xor(s, 8);
      if (fr == 0) atomicAdd(&a_ws[m], s);
    }
  }
}

// ---------------------------------------------------------------------------
// softmax over s for each n (b3 omitted: scalar shift is softmax-invariant).
// Also zero-inits c_out[n*1024..] (runs before weighted_sum's atomics).
// ---------------------------------------------------------------------------
__global__ void softmax_col(const float* __restrict__ a_ws,
                            float* __restrict__ alpha,
                            float* __restrict__ c_out) {
  int n = blockIdx.x;
  int t = threadIdx.x;
  __shared__ float red[256];
#pragma unroll
  for (int q = 0; q < 4; ++q) c_out[(size_t)n * 1024 + q * 256 + t] = 0.f;
  float v[4];
  float mx = -1e30f;
#pragma unroll
  for (int q = 0; q < 4; ++q) {
    v[q] = a_ws[(size_t)(t + q * 256) * 64 + n];
    mx = fmaxf(mx, v[q]);
  }
  red[t] = mx; __syncthreads();
  for (int off = 128; off > 0; off >>= 1) {
    if (t < off) red[t] = fmaxf(red[t], red[t + off]);
    __syncthreads();
  }
  mx = red[0];
  __syncthreads();
  float sum = 0.f;
#pragma unroll
  for (int q = 0; q < 4; ++q) { v[q] = __expf(v[q] - mx); sum += v[q]; }
  red[t] = sum; __syncthreads();
  for (int off = 128; off > 0; off >>= 1) {
    if (t < off) red[t] += red[t + off];
    __syncthreads();
  }
  float inv = 1.f / red[0];
#pragma unroll
  for (int q = 0; q < 4; ++q)
    alpha[(size_t)(t + q * 256) * 64 + n] = v[q] * inv;
}

// ---------------------------------------------------------------------------
// c[n][h] += sum_{s in chunk sc} alpha[s,n] * oe16[s,n,h]
// ---------------------------------------------------------------------------
__global__ void weighted_sum(const _Float16* __restrict__ oe,
                             const float* __restrict__ alpha,
                             float* __restrict__ cout) {
  int n = blockIdx.x & 63;
  int sc = blockIdx.x >> 6;
  int t = threadIdx.x;
  __shared__ float al[64];
  if (t < 64) al[t] = alpha[(size_t)(sc * 64 + t) * 64 + n];
  __syncthreads();
  float a0 = 0.f, a1 = 0.f, a2 = 0.f, a3 = 0.f;
#pragma unroll 4
  for (int sl = 0; sl < 64; ++sl) {
    float a = al[sl];
    int s = sc * 64 + sl;
    half4 x = *(const half4*)(oe + (size_t)(s * 64 + n) * 1024 + t * 4);
    a0 += a * (float)x[0]; a1 += a * (float)x[1];
    a2 += a * (float)x[2]; a3 += a * (float)x[3];
  }
  float* c = cout + (size_t)n * 1024 + t * 4;
  atomicAdd(c + 0, a0);
  atomicAdd(c + 1, a1);
  atomicAdd(c + 2, a2);
  atomicAdd(c + 3, a3);
}

// ---------------------------------------------------------------------------
extern "C" void kernel_launch(void* const* d_in, const int* in_sizes, int n_in,
                              void* d_out, int out_size, void* d_ws,
                              size_t ws_size, hipStream_t stream) {
  const float* out_e    = (const float*)d_in[0];
  const float* hidden_d = (const float*)d_in[1];
  const float* W1       = (const float*)d_in[2];
  const float* b1       = (const float*)d_in[3];
  const float* W2       = (const float*)d_in[4];
  const float* b2       = (const float*)d_in[5];
  const float* W3       = (const float*)d_in[6];
  // d_in[7] = b3: scalar shift before softmax -> cancels; unused.

  char* ws = (char*)d_ws;
  _Float16* oe16 = (_Float16*)ws;                               // 128 MB
  _Float16* w216 = (_Float16*)(ws + 134217728);                 // 2 MB
  float* u1   = (float*)(ws + 134217728 + 2097152);             // 256 KB
  float* a_ws = (float*)(ws + 134217728 + 2097152 + 262144);    // 256 KB

  float* c_out = (float*)d_out;            // [64][1024]
  float* alpha = (float*)d_out + 65536;    // [1024][64]

  hipLaunchKernelGGL(cvt_f32_f16, dim3(4096), dim3(256), 0, stream,
                     out_e, oe16, 67108864 / 8);
  hipLaunchKernelGGL(cvt_f32_f16, dim3(512), dim3(256), 0, stream,
                     W2, w216, 1048576 / 8);
  hipLaunchKernelGGL(u1_kernel, dim3(256), dim3(256), 0, stream,
                     hidden_d, W1, b1, b2, u1, a_ws);
  hipLaunchKernelGGL(fused_gemm_tanh, dim3(4096), dim3(256), 0, stream,
                     oe16, w216, u1, W3, a_ws);
  hipLaunchKernelGGL(softmax_col, dim3(64), dim3(256), 0, stream,
                     a_ws, alpha, c_out);
  hipLaunchKernelGGL(weighted_sum, dim3(1024), dim3(256), 0, stream,
                     oe16, alpha, c_out);
}

// Round 8
// 648.432 us; speedup vs baseline: 1.0508x; 1.0277x over previous
//
#include <hip/hip_runtime.h>
#include <hip/hip_fp16.h>

// Problem constants (fixed by the reference)
#define S_LEN 1024
#define N_B   64
#define H_DIM 1024
#define I_DIM 1024

typedef __attribute__((ext_vector_type(8))) _Float16 half8;
typedef __attribute__((ext_vector_type(4))) _Float16 half4;
typedef __attribute__((ext_vector_type(4))) float    f32x4;

// ---------------------------------------------------------------------------
// async global->LDS 16B helper (wave-uniform LDS base + lane*16 layout)
// ---------------------------------------------------------------------------
__device__ __forceinline__ void gload16(const void* g, void* l) {
  __builtin_amdgcn_global_load_lds(
      (const __attribute__((address_space(1))) unsigned int*)g,
      (__attribute__((address_space(3))) unsigned int*)l, 16, 0, 0);
}

// ---------------------------------------------------------------------------
// ONE setup kernel, role-split by blockIdx (graph-node reduction):
//   blocks [0,4096)    : cvt out_e fp32->fp16 (384 MB stream, the long pole)
//   blocks [4096,4160) : cvt W2 fp32->fp16 (4 MB)
//   blocks [4160,4416) : u1[n][i] = hd[n]*W1[i] + b1 + b2; zero a_ws, c_out
// ---------------------------------------------------------------------------
__global__ __launch_bounds__(256) void setup_kernel(
    const float* __restrict__ out_e, const float* __restrict__ hd,
    const float* __restrict__ W1, const float* __restrict__ b1,
    const float* __restrict__ b2, const float* __restrict__ W2,
    _Float16* __restrict__ oe16, _Float16* __restrict__ w216,
    float* __restrict__ u1, float* __restrict__ a_ws,
    float* __restrict__ c_out) {
  __shared__ float hs[4 * 1024];
  const int bx = blockIdx.x;
  const int t = threadIdx.x;

  if (bx < 4096) {  // ---- cvt out_e: 67108864 elems = 8388608 half8 groups
    const float4* s4 = (const float4*)out_e;
    half8* d8 = (half8*)oe16;
    int i = bx * 256 + t;
#pragma unroll
    for (int r = 0; r < 8; ++r, i += 1048576) {
      float4 a = s4[2 * i], b = s4[2 * i + 1];
      half8 h;
      h[0] = (_Float16)a.x; h[1] = (_Float16)a.y;
      h[2] = (_Float16)a.z; h[3] = (_Float16)a.w;
      h[4] = (_Float16)b.x; h[5] = (_Float16)b.y;
      h[6] = (_Float16)b.z; h[7] = (_Float16)b.w;
      d8[i] = h;
    }
    return;
  }
  if (bx < 4160) {  // ---- cvt W2: 1048576 elems = 131072 half8 groups
    const float4* s4 = (const float4*)W2;
    half8* d8 = (half8*)w216;
    int i = (bx - 4096) * 256 + t;
#pragma unroll
    for (int r = 0; r < 8; ++r, i += 16384) {
      float4 a = s4[2 * i], b = s4[2 * i + 1];
      half8 h;
      h[0] = (_Float16)a.x; h[1] = (_Float16)a.y;
      h[2] = (_Float16)a.z; h[3] = (_Float16)a.w;
      h[4] = (_Float16)b.x; h[5] = (_Float16)b.y;
      h[6] = (_Float16)b.z; h[7] = (_Float16)b.w;
      d8[i] = h;
    }
    return;
  }
  // ---- u1 role (256 blocks) + zero the two atomic targets
  const int local = bx - 4160;
  a_ws[local * 256 + t] = 0.f;
  c_out[local * 256 + t] = 0.f;

  const int nb = local & 15;
  const int ib = local >> 4;
  const int n0 = nb * 4;

  const float4* g4 = (const float4*)(hd + (size_t)n0 * 1024);
  float4* h4 = (float4*)hs;
#pragma unroll
  for (int r = 0; r < 4; ++r) h4[r * 256 + t] = g4[r * 256 + t];
  __syncthreads();

  int il = t >> 2, q = t & 3;
  int i = ib * 64 + il;
  const float4* w4 = (const float4*)(W1 + (size_t)i * 1024 + q * 256);
  float s0 = 0.f, s1 = 0.f, s2 = 0.f, s3 = 0.f;
  for (int hh = 0; hh < 64; ++hh) {
    float4 wv = w4[hh];
    int hb = q * 256 + hh * 4;
    float4 v0 = *(const float4*)&hs[0 * 1024 + hb];
    float4 v1 = *(const float4*)&hs[1 * 1024 + hb];
    float4 v2 = *(const float4*)&hs[2 * 1024 + hb];
    float4 v3 = *(const float4*)&hs[3 * 1024 + hb];
    s0 += wv.x * v0.x + wv.y * v0.y + wv.z * v0.z + wv.w * v0.w;
    s1 += wv.x * v1.x + wv.y * v1.y + wv.z * v1.z + wv.w * v1.w;
    s2 += wv.x * v2.x + wv.y * v2.y + wv.z * v2.z + wv.w * v2.w;
    s3 += wv.x * v3.x + wv.y * v3.y + wv.z * v3.z + wv.w * v3.w;
  }
  s0 += __shfl_xor(s0, 1); s0 += __shfl_xor(s0, 2);
  s1 += __shfl_xor(s1, 1); s1 += __shfl_xor(s1, 2);
  s2 += __shfl_xor(s2, 1); s2 += __shfl_xor(s2, 2);
  s3 += __shfl_xor(s3, 1); s3 += __shfl_xor(s3, 2);
  if (q == 0) {
    float bb = b1[i] + b2[i];
    u1[(size_t)(n0 + 0) * 1024 + i] = s0 + bb;
    u1[(size_t)(n0 + 1) * 1024 + i] = s1 + bb;
    u1[(size_t)(n0 + 2) * 1024 + i] = s2 + bb;
    u1[(size_t)(n0 + 3) * 1024 + i] = s3 + bb;
  }
}

// ---------------------------------------------------------------------------
// Main fused kernel:  a_ws[m] += sum_i W3[i] * tanh( A[m]·W2[i] + u1[m&63][i] )
// R2-VERBATIM m97 structure (proven 226us): 128x128 tile, BK=32, 4 waves,
// 16x16x32 fp16 MFMA, double-buffered LDS via global_load_lds width-16.
// No LDS swizzle: the b128 read pattern is already bank-BALANCED (8/bank =
// b128 floor); R5's swizzle changed nothing but cost VGPR/occupancy.
// grid: 4096; XCD swizzle keeps one A-panel's 8 cb on one XCD.
// ---------------------------------------------------------------------------
__global__ __launch_bounds__(256) void fused_gemm_tanh(
    const _Float16* __restrict__ A,   // [65536][1024] out_e fp16
    const _Float16* __restrict__ B,   // [1024][1024]  W2 fp16
    const float* __restrict__ u1,     // [64][1024] includes b1+b2
    const float* __restrict__ W3,     // [1024]
    float* __restrict__ a_ws)         // [65536] pre-zeroed, atomic target
{
  __shared__ __align__(16) _Float16 As[2][128 * 32];  // 8KB per buf
  __shared__ __align__(16) _Float16 Bs[2][128 * 32];

  const int t = threadIdx.x;
  const int lane = t & 63;
  const int w = t >> 6;
  const int wr = w >> 1, wc = w & 1;
  const int bx = blockIdx.x;
  const int xcd = bx & 7;
  const int j = bx >> 3;
  const int rb = xcd + ((j >> 3) << 3);   // 0..511
  const int cb = j & 7;                   // 0..7
  const int m0 = rb * 128, i0 = cb * 128;

  const int strow = t >> 2;
  const int stcol = (t & 3) * 8;
  const _Float16* gA = A + (size_t)(m0 + strow) * 1024 + stcol;
  const _Float16* gB = B + (size_t)(i0 + strow) * 1024 + stcol;
  const int ldsoff = strow * 32 + stcol;  // linear: byte = t*16

  f32x4 acc[4][4] = {};

  gload16(gA,             &As[0][ldsoff]);
  gload16(gA + 64 * 1024, &As[0][ldsoff + 64 * 32]);
  gload16(gB,             &Bs[0][ldsoff]);
  gload16(gB + 64 * 1024, &Bs[0][ldsoff + 64 * 32]);
  __syncthreads();  // compiler drains vmcnt before s_barrier

  const int fr = lane & 15;     // A-row / B-col within fragment
  const int kg = lane >> 4;     // k-group 0..3 (8 contiguous k each)
  const int aoff = (wr * 64 + fr) * 32 + kg * 8;
  const int boff = (wc * 64 + fr) * 32 + kg * 8;

  for (int kt = 0; kt < 32; ++kt) {
    const int buf = kt & 1;
    if (kt < 31) {
      const _Float16* gA2 = gA + (kt + 1) * 32;
      const _Float16* gB2 = gB + (kt + 1) * 32;
      gload16(gA2,             &As[buf ^ 1][ldsoff]);
      gload16(gA2 + 64 * 1024, &As[buf ^ 1][ldsoff + 64 * 32]);
      gload16(gB2,             &Bs[buf ^ 1][ldsoff]);
      gload16(gB2 + 64 * 1024, &Bs[buf ^ 1][ldsoff + 64 * 32]);
    }
    half8 af[4], bf[4];
#pragma unroll
    for (int mi = 0; mi < 4; ++mi)
      af[mi] = *(const half8*)&As[buf][aoff + mi * 16 * 32];
#pragma unroll
    for (int ni = 0; ni < 4; ++ni)
      bf[ni] = *(const half8*)&Bs[buf][boff + ni * 16 * 32];
#pragma unroll
    for (int mi = 0; mi < 4; ++mi)
#pragma unroll
      for (int ni = 0; ni < 4; ++ni)
        acc[mi][ni] = __builtin_amdgcn_mfma_f32_16x16x32_f16(
            af[mi], bf[ni], acc[mi][ni], 0, 0, 0);
    __syncthreads();
  }

  float w3v[4];
#pragma unroll
  for (int ni = 0; ni < 4; ++ni)
    w3v[ni] = W3[i0 + wc * 64 + ni * 16 + fr];

#pragma unroll
  for (int mi = 0; mi < 4; ++mi) {
#pragma unroll
    for (int jj = 0; jj < 4; ++jj) {
      int m = m0 + wr * 64 + mi * 16 + kg * 4 + jj;  // C/D row=(lane>>4)*4+reg
      int n = m & 63;
      const float* u1row = u1 + (size_t)n * 1024 + i0 + wc * 64;
      float s = 0.f;
#pragma unroll
      for (int ni = 0; ni < 4; ++ni) {
        float e = acc[mi][ni][jj] + u1row[ni * 16 + fr];  // C/D col=lane&15
        float th = 1.f - 2.f / (__expf(2.f * e) + 1.f);   // tanh, inf/0-safe
        s += th * w3v[ni];
      }
      s += __shfl_xor(s, 1);
      s += __shfl_xor(s, 2);
      s += __shfl_xor(s, 4);
      s += __shfl_xor(s, 8);
      if (fr == 0) atomicAdd(&a_ws[m], s);
    }
  }
}

// ---------------------------------------------------------------------------
// Fused softmax + weighted-sum. grid: 1024 blocks = (n = bx&63, sc = bx>>6).
// Each block redundantly recomputes the full softmax reduction over s for its
// n (a_ws column: 4 KB, L2-resident -> redundancy free), writes the 64 alpha
// rows of its chunk, then accumulates c[n] over its chunk via atomics.
// b3 omitted: uniform scalar shift is softmax-invariant.
// ---------------------------------------------------------------------------
__global__ __launch_bounds__(256) void softmax_wsum(
    const float* __restrict__ a_ws, const _Float16* __restrict__ oe,
    float* __restrict__ alpha, float* __restrict__ cout) {
  const int n = blockIdx.x & 63;
  const int sc = blockIdx.x >> 6;
  const int t = threadIdx.x;
  __shared__ float red[256];
  __shared__ float al[64];

  float v[4];
  float mx = -1e30f;
#pragma unroll
  for (int q = 0; q < 4; ++q) {
    v[q] = a_ws[(size_t)(t + q * 256) * 64 + n];
    mx = fmaxf(mx, v[q]);
  }
  red[t] = mx; __syncthreads();
  for (int off = 128; off > 0; off >>= 1) {
    if (t < off) red[t] = fmaxf(red[t], red[t + off]);
    __syncthreads();
  }
  mx = red[0];
  __syncthreads();
  float sum = 0.f;
#pragma unroll
  for (int q = 0; q < 4; ++q) { v[q] = __expf(v[q] - mx); sum += v[q]; }
  red[t] = sum; __syncthreads();
  for (int off = 128; off > 0; off >>= 1) {
    if (t < off) red[t] += red[t + off];
    __syncthreads();
  }
  const float inv = 1.f / red[0];

  // threads owning this chunk's s-range publish alpha (s = sc*64 + (t-tlo))
  const int q0 = sc >> 2;
  const int tlo = (sc & 3) * 64;
  if (t >= tlo && t < tlo + 64) {
    float a = v[q0] * inv;
    al[t - tlo] = a;
    alpha[(size_t)(sc * 64 + (t - tlo)) * 64 + n] = a;
  }
  __syncthreads();

  // weighted sum over this chunk; thread t covers h = 4t..4t+3
  float a0 = 0.f, a1 = 0.f, a2 = 0.f, a3 = 0.f;
#pragma unroll 4
  for (int sl = 0; sl < 64; ++sl) {
    float a = al[sl];
    int s = sc * 64 + sl;
    half4 x = *(const half4*)(oe + (size_t)(s * 64 + n) * 1024 + t * 4);
    a0 += a * (float)x[0]; a1 += a * (float)x[1];
    a2 += a * (float)x[2]; a3 += a * (float)x[3];
  }
  float* c = cout + (size_t)n * 1024 + t * 4;
  atomicAdd(c + 0, a0);
  atomicAdd(c + 1, a1);
  atomicAdd(c + 2, a2);
  atomicAdd(c + 3, a3);
}

// ---------------------------------------------------------------------------
extern "C" void kernel_launch(void* const* d_in, const int* in_sizes, int n_in,
                              void* d_out, int out_size, void* d_ws,
                              size_t ws_size, hipStream_t stream) {
  const float* out_e    = (const float*)d_in[0];
  const float* hidden_d = (const float*)d_in[1];
  const float* W1       = (const float*)d_in[2];
  const float* b1       = (const float*)d_in[3];
  const float* W2       = (const float*)d_in[4];
  const float* b2       = (const float*)d_in[5];
  const float* W3       = (const float*)d_in[6];
  // d_in[7] = b3: scalar shift before softmax -> cancels; unused.

  char* ws = (char*)d_ws;
  _Float16* oe16 = (_Float16*)ws;                               // 128 MB
  _Float16* w216 = (_Float16*)(ws + 134217728);                 // 2 MB
  float* u1   = (float*)(ws + 134217728 + 2097152);             // 256 KB
  float* a_ws = (float*)(ws + 134217728 + 2097152 + 262144);    // 256 KB

  float* c_out = (float*)d_out;            // [64][1024]
  float* alpha = (float*)d_out + 65536;    // [1024][64]

  hipLaunchKernelGGL(setup_kernel, dim3(4416), dim3(256), 0, stream,
                     out_e, hidden_d, W1, b1, b2, W2,
                     oe16, w216, u1, a_ws, c_out);
  hipLaunchKernelGGL(fused_gemm_tanh, dim3(4096), dim3(256), 0, stream,
                     oe16, w216, u1, W3, a_ws);
  hipLaunchKernelGGL(softmax_wsum, dim3(1024), dim3(256), 0, stream,
                     a_ws, oe16, alpha, c_out);
}

// Round 9
// 634.969 us; speedup vs baseline: 1.0731x; 1.0212x over previous
//
#include <hip/hip_runtime.h>
#include <hip/hip_fp16.h>

// Problem constants (fixed by the reference)
#define S_LEN 1024
#define N_B   64
#define H_DIM 1024
#define I_DIM 1024

typedef __attribute__((ext_vector_type(8))) _Float16 half8;
typedef __attribute__((ext_vector_type(4))) _Float16 half4;
typedef __attribute__((ext_vector_type(4))) float    f32x4;

// ---------------------------------------------------------------------------
// async global->LDS 16B helper (wave-uniform LDS base + lane*16 layout)
// ---------------------------------------------------------------------------
__device__ __forceinline__ void gload16(const void* g, void* l) {
  __builtin_amdgcn_global_load_lds(
      (const __attribute__((address_space(1))) unsigned int*)g,
      (__attribute__((address_space(3))) unsigned int*)l, 16, 0, 0);
}

// ---------------------------------------------------------------------------
// ONE setup kernel, role-split by blockIdx (R8-verified):
//   blocks [0,4096)    : cvt out_e fp32->fp16 (384 MB stream, the long pole)
//   blocks [4096,4160) : cvt W2 fp32->fp16 (4 MB)
//   blocks [4160,4416) : u1[n][i] = hd[n]*W1[i] + b1 + b2; zero a_ws, c_out
// ---------------------------------------------------------------------------
__global__ __launch_bounds__(256) void setup_kernel(
    const float* __restrict__ out_e, const float* __restrict__ hd,
    const float* __restrict__ W1, const float* __restrict__ b1,
    const float* __restrict__ b2, const float* __restrict__ W2,
    _Float16* __restrict__ oe16, _Float16* __restrict__ w216,
    float* __restrict__ u1, float* __restrict__ a_ws,
    float* __restrict__ c_out) {
  __shared__ float hs[4 * 1024];
  const int bx = blockIdx.x;
  const int t = threadIdx.x;

  if (bx < 4096) {  // ---- cvt out_e: 67108864 elems = 8388608 half8 groups
    const float4* s4 = (const float4*)out_e;
    half8* d8 = (half8*)oe16;
    int i = bx * 256 + t;
#pragma unroll
    for (int r = 0; r < 8; ++r, i += 1048576) {
      float4 a = s4[2 * i], b = s4[2 * i + 1];
      half8 h;
      h[0] = (_Float16)a.x; h[1] = (_Float16)a.y;
      h[2] = (_Float16)a.z; h[3] = (_Float16)a.w;
      h[4] = (_Float16)b.x; h[5] = (_Float16)b.y;
      h[6] = (_Float16)b.z; h[7] = (_Float16)b.w;
      d8[i] = h;
    }
    return;
  }
  if (bx < 4160) {  // ---- cvt W2: 1048576 elems = 131072 half8 groups
    const float4* s4 = (const float4*)W2;
    half8* d8 = (half8*)w216;
    int i = (bx - 4096) * 256 + t;
#pragma unroll
    for (int r = 0; r < 8; ++r, i += 16384) {
      float4 a = s4[2 * i], b = s4[2 * i + 1];
      half8 h;
      h[0] = (_Float16)a.x; h[1] = (_Float16)a.y;
      h[2] = (_Float16)a.z; h[3] = (_Float16)a.w;
      h[4] = (_Float16)b.x; h[5] = (_Float16)b.y;
      h[6] = (_Float16)b.z; h[7] = (_Float16)b.w;
      d8[i] = h;
    }
    return;
  }
  // ---- u1 role (256 blocks) + zero the two atomic targets
  const int local = bx - 4160;
  a_ws[local * 256 + t] = 0.f;
  c_out[local * 256 + t] = 0.f;

  const int nb = local & 15;
  const int ib = local >> 4;
  const int n0 = nb * 4;

  const float4* g4 = (const float4*)(hd + (size_t)n0 * 1024);
  float4* h4 = (float4*)hs;
#pragma unroll
  for (int r = 0; r < 4; ++r) h4[r * 256 + t] = g4[r * 256 + t];
  __syncthreads();

  int il = t >> 2, q = t & 3;
  int i = ib * 64 + il;
  const float4* w4 = (const float4*)(W1 + (size_t)i * 1024 + q * 256);
  float s0 = 0.f, s1 = 0.f, s2 = 0.f, s3 = 0.f;
  for (int hh = 0; hh < 64; ++hh) {
    float4 wv = w4[hh];
    int hb = q * 256 + hh * 4;
    float4 v0 = *(const float4*)&hs[0 * 1024 + hb];
    float4 v1 = *(const float4*)&hs[1 * 1024 + hb];
    float4 v2 = *(const float4*)&hs[2 * 1024 + hb];
    float4 v3 = *(const float4*)&hs[3 * 1024 + hb];
    s0 += wv.x * v0.x + wv.y * v0.y + wv.z * v0.z + wv.w * v0.w;
    s1 += wv.x * v1.x + wv.y * v1.y + wv.z * v1.z + wv.w * v1.w;
    s2 += wv.x * v2.x + wv.y * v2.y + wv.z * v2.z + wv.w * v2.w;
    s3 += wv.x * v3.x + wv.y * v3.y + wv.z * v3.z + wv.w * v3.w;
  }
  s0 += __shfl_xor(s0, 1); s0 += __shfl_xor(s0, 2);
  s1 += __shfl_xor(s1, 1); s1 += __shfl_xor(s1, 2);
  s2 += __shfl_xor(s2, 1); s2 += __shfl_xor(s2, 2);
  s3 += __shfl_xor(s3, 1); s3 += __shfl_xor(s3, 2);
  if (q == 0) {
    float bb = b1[i] + b2[i];
    u1[(size_t)(n0 + 0) * 1024 + i] = s0 + bb;
    u1[(size_t)(n0 + 1) * 1024 + i] = s1 + bb;
    u1[(size_t)(n0 + 2) * 1024 + i] = s2 + bb;
    u1[(size_t)(n0 + 3) * 1024 + i] = s3 + bb;
  }
}

// ---------------------------------------------------------------------------
// Main fused kernel: a_ws[m] += sum_i W3[i]*tanh(A[m]·W2[i] + u1[m&63][i])
// 256x256 tile, BK=32, 8 waves (2Mx4N), 4 LDS buffers, 3-deep prefetch,
// ONE counted vmcnt(8)+s_barrier per K-tile, NO drain until tail.
// Race-freedom: RAW gated by vmcnt(8)+barrier (stage kt issued at kt-3);
// WAR safe because stage(kt+3) is issued after iter-kt's barrier, and all
// reads of that region (iter kt-1) complete before their MFMA-use, which
// precedes that barrier in program order. Fragment/epilogue math = R4
// (verified passing). gloads interleave inside MFMA phases; setprio wraps
// MFMA clusters. grid: 1024 blocks; XCD swizzle: one A-panel per XCD.
// ---------------------------------------------------------------------------
__global__ __launch_bounds__(512, 2) void fused_gemm_tanh(
    const _Float16* __restrict__ A,   // [65536][1024] out_e fp16
    const _Float16* __restrict__ B,   // [1024][1024]  W2 fp16
    const float* __restrict__ u1,     // [64][1024] includes b1+b2
    const float* __restrict__ W3,     // [1024]
    float* __restrict__ a_ws)         // [65536] pre-zeroed, atomic target
{
  __shared__ __align__(16) _Float16 As[4][256 * 32];  // 16 KB per buf
  __shared__ __align__(16) _Float16 Bs[4][256 * 32];  // total 128 KB

  const int t = threadIdx.x;            // 0..511
  const int lane = t & 63;
  const int w = t >> 6;
  const int wr = w >> 2, wc = w & 3;    // 2 x 4 wave grid
  const int bx = blockIdx.x;
  const int xcd = bx & 7;
  const int j = bx >> 3;                // 0..127
  const int rb = xcd + ((j >> 2) << 3); // 0..255
  const int cb = j & 3;                 // 0..3
  const int m0 = rb * 256, i0 = cb * 256;

  const int fr = lane & 15;             // fragment row (A-row / B-col)
  const int kg = lane >> 4;             // k-group 0..3

  // staging: thread t covers (row t>>2 [+128 on 2nd call], 16B-unit t&3)
  const _Float16* gA0 = A + (size_t)(m0 + (t >> 2)) * 1024 + (t & 3) * 8;
  const _Float16* gB0 = B + (size_t)(i0 + (t >> 2)) * 1024 + (t & 3) * 8;
  const int ldst = t * 8;               // halves; LDS byte = t*16 (linear)

#define STAGE_A(kt) do { int b_ = (kt) & 3; int kc = (kt) * 32;      \
    gload16(gA0 + kc,          &As[b_][ldst]);                        \
    gload16(gA0 + kc + 131072, &As[b_][ldst + 4096]); } while (0)
#define STAGE_B(kt) do { int b_ = (kt) & 3; int kc = (kt) * 32;      \
    gload16(gB0 + kc,          &Bs[b_][ldst]);                        \
    gload16(gB0 + kc + 131072, &Bs[b_][ldst + 4096]); } while (0)

  f32x4 acc[8][4] = {};

  // prologue: 3 K-tiles in flight (12 gloads)
  STAGE_A(0); STAGE_B(0);
  STAGE_A(1); STAGE_B(1);
  STAGE_A(2); STAGE_B(2);

  const int aoff = (wr * 128 + fr) * 32 + kg * 8;  // + fm*512
  const int boff = (wc * 64 + fr) * 32 + kg * 8;   // + fn*512

#define GATE(N) do {                                           \
    asm volatile("s_waitcnt vmcnt(" #N ")" ::: "memory");      \
    asm volatile("s_barrier" ::: "memory"); } while (0)

  // One iteration: 2 phases {ds_read frags, interleaved stage, 16 MFMA}
#define PHASES(kt, DO_STAGE) do {                                         \
    const _Float16* As_ = &As[(kt) & 3][0];                               \
    const _Float16* Bs_ = &Bs[(kt) & 3][0];                               \
    half8 bf[4], af[4];                                                   \
    _Pragma("unroll") for (int ni = 0; ni < 4; ++ni)                      \
      bf[ni] = *(const half8*)&Bs_[boff + ni * 512];                      \
    _Pragma("unroll") for (int mi = 0; mi < 4; ++mi)                      \
      af[mi] = *(const half8*)&As_[aoff + mi * 512];                      \
    if (DO_STAGE) STAGE_A((kt) + 3);                                      \
    __builtin_amdgcn_s_setprio(1);                                        \
    _Pragma("unroll") for (int mi = 0; mi < 4; ++mi)                      \
      _Pragma("unroll") for (int ni = 0; ni < 4; ++ni)                    \
        acc[mi][ni] = __builtin_amdgcn_mfma_f32_16x16x32_f16(             \
            af[mi], bf[ni], acc[mi][ni], 0, 0, 0);                        \
    __builtin_amdgcn_s_setprio(0);                                        \
    _Pragma("unroll") for (int mi = 0; mi < 4; ++mi)                      \
      af[mi] = *(const half8*)&As_[aoff + (4 + mi) * 512];                \
    if (DO_STAGE) STAGE_B((kt) + 3);                                      \
    __builtin_amdgcn_s_setprio(1);                                        \
    _Pragma("unroll") for (int mi = 0; mi < 4; ++mi)                      \
      _Pragma("unroll") for (int ni = 0; ni < 4; ++ni)                    \
        acc[4 + mi][ni] = __builtin_amdgcn_mfma_f32_16x16x32_f16(         \
            af[mi], bf[ni], acc[4 + mi][ni], 0, 0, 0);                    \
    __builtin_amdgcn_s_setprio(0); } while (0)

  // K = 1024 -> 32 K-tiles. Steady gate vmcnt(8): stages kt+1,kt+2 in flight.
  for (int kt = 0; kt < 29; ++kt) { GATE(8); PHASES(kt, 1); }
  GATE(8); PHASES(29, 0);   // stages 30,31 outstanding
  GATE(4); PHASES(30, 0);   // stage 31 outstanding
  GATE(0); PHASES(31, 0);   // drain

#undef PHASES
#undef GATE
#undef STAGE_A
#undef STAGE_B

  // Epilogue (R4-verified): e = acc + u1; tanh; dot W3; shfl-reduce; atomic.
  float w3v[4];
#pragma unroll
  for (int ni = 0; ni < 4; ++ni)
    w3v[ni] = W3[i0 + wc * 64 + ni * 16 + fr];
  const float* u1base = u1 + i0 + wc * 64 + fr;

#pragma unroll
  for (int mi = 0; mi < 8; ++mi) {
#pragma unroll
    for (int jj = 0; jj < 4; ++jj) {
      int m = m0 + wr * 128 + mi * 16 + kg * 4 + jj;  // C/D row=(lane>>4)*4+reg
      const float* u1row = u1base + (size_t)(m & 63) * 1024;
      float s = 0.f;
#pragma unroll
      for (int ni = 0; ni < 4; ++ni) {
        float e = acc[mi][ni][jj] + u1row[ni * 16];   // C/D col=lane&15
        float th = 1.f - 2.f / (__expf(2.f * e) + 1.f);  // tanh, inf/0-safe
        s += th * w3v[ni];
      }
      s += __shfl_xor(s, 1);
      s += __shfl_xor(s, 2);
      s += __shfl_xor(s, 4);
      s += __shfl_xor(s, 8);
      if (fr == 0) atomicAdd(&a_ws[m], s);
    }
  }
}

// ---------------------------------------------------------------------------
// Fused softmax + weighted-sum (R8-verified). grid: 1024 = (n=bx&63, sc=bx>>6)
// ---------------------------------------------------------------------------
__global__ __launch_bounds__(256) void softmax_wsum(
    const float* __restrict__ a_ws, const _Float16* __restrict__ oe,
    float* __restrict__ alpha, float* __restrict__ cout) {
  const int n = blockIdx.x & 63;
  const int sc = blockIdx.x >> 6;
  const int t = threadIdx.x;
  __shared__ float red[256];
  __shared__ float al[64];

  float v[4];
  float mx = -1e30f;
#pragma unroll
  for (int q = 0; q < 4; ++q) {
    v[q] = a_ws[(size_t)(t + q * 256) * 64 + n];
    mx = fmaxf(mx, v[q]);
  }
  red[t] = mx; __syncthreads();
  for (int off = 128; off > 0; off >>= 1) {
    if (t < off) red[t] = fmaxf(red[t], red[t + off]);
    __syncthreads();
  }
  mx = red[0];
  __syncthreads();
  float sum = 0.f;
#pragma unroll
  for (int q = 0; q < 4; ++q) { v[q] = __expf(v[q] - mx); sum += v[q]; }
  red[t] = sum; __syncthreads();
  for (int off = 128; off > 0; off >>= 1) {
    if (t < off) red[t] += red[t + off];
    __syncthreads();
  }
  const float inv = 1.f / red[0];

  const int q0 = sc >> 2;
  const int tlo = (sc & 3) * 64;
  if (t >= tlo && t < tlo + 64) {
    float a = v[q0] * inv;
    al[t - tlo] = a;
    alpha[(size_t)(sc * 64 + (t - tlo)) * 64 + n] = a;
  }
  __syncthreads();

  float a0 = 0.f, a1 = 0.f, a2 = 0.f, a3 = 0.f;
#pragma unroll 4
  for (int sl = 0; sl < 64; ++sl) {
    float a = al[sl];
    int s = sc * 64 + sl;
    half4 x = *(const half4*)(oe + (size_t)(s * 64 + n) * 1024 + t * 4);
    a0 += a * (float)x[0]; a1 += a * (float)x[1];
    a2 += a * (float)x[2]; a3 += a * (float)x[3];
  }
  float* c = cout + (size_t)n * 1024 + t * 4;
  atomicAdd(c + 0, a0);
  atomicAdd(c + 1, a1);
  atomicAdd(c + 2, a2);
  atomicAdd(c + 3, a3);
}

// ---------------------------------------------------------------------------
extern "C" void kernel_launch(void* const* d_in, const int* in_sizes, int n_in,
                              void* d_out, int out_size, void* d_ws,
                              size_t ws_size, hipStream_t stream) {
  const float* out_e    = (const float*)d_in[0];
  const float* hidden_d = (const float*)d_in[1];
  const float* W1       = (const float*)d_in[2];
  const float* b1       = (const float*)d_in[3];
  const float* W2       = (const float*)d_in[4];
  const float* b2       = (const float*)d_in[5];
  const float* W3       = (const float*)d_in[6];
  // d_in[7] = b3: scalar shift before softmax -> cancels; unused.

  char* ws = (char*)d_ws;
  _Float16* oe16 = (_Float16*)ws;                               // 128 MB
  _Float16* w216 = (_Float16*)(ws + 134217728);                 // 2 MB
  float* u1   = (float*)(ws + 134217728 + 2097152);             // 256 KB
  float* a_ws = (float*)(ws + 134217728 + 2097152 + 262144);    // 256 KB

  float* c_out = (float*)d_out;            // [64][1024]
  float* alpha = (float*)d_out + 65536;    // [1024][64]

  hipLaunchKernelGGL(setup_kernel, dim3(4416), dim3(256), 0, stream,
                     out_e, hidden_d, W1, b1, b2, W2,
                     oe16, w216, u1, a_ws, c_out);
  hipLaunchKernelGGL(fused_gemm_tanh, dim3(1024), dim3(512), 0, stream,
                     oe16, w216, u1, W3, a_ws);
  hipLaunchKernelGGL(softmax_wsum, dim3(1024), dim3(256), 0, stream,
                     a_ws, oe16, alpha, c_out);
}